// Round 1
// baseline (505.072 us; speedup 1.0000x reference)
//
#include <hip/hip_runtime.h>

// KnowledgeConsistentAttention: out = softmax_q( pool3x3(F) . K^T ) . K,  K = normalize(F+eps)
// Key identity: pool3x3 acts only on the p index of S = F.K^T, so pool(F.K^T) = pool(F).K^T.
// => flash-attention-style fused kernel with Q=G=pool3x3(F), K=V=normalize(F+eps).
// |S| <= ~60 so exp(S) fits fp32 -> no max subtraction; accumulate unnormalized O and row-sum l,
// divide at the end. bf16 MFMA (16x16x32) throughout; fp32 accumulation.

#define EPSV 1e-7f

typedef __bf16 bf16x8 __attribute__((ext_vector_type(8)));
typedef float f32x4 __attribute__((ext_vector_type(4)));

__device__ __forceinline__ unsigned short f2bf(float f) {
    union { float f; unsigned int u; } x; x.f = f;
    unsigned int r = x.u + 0x7FFFu + ((x.u >> 16) & 1u);
    return (unsigned short)(r >> 16);
}

__device__ __forceinline__ f32x4 mfma16(bf16x8 a, bf16x8 b, f32x4 c) {
    return __builtin_amdgcn_mfma_f32_16x16x32_bf16(a, b, c, 0, 0, 0);
}

// ---------------- prep 1: K_hi (bf16 normalized rows) + Vt (transposed copy) ----------------
// grid (64 qblocks, 4 batch), 256 threads. Each block: 64 q rows.
__global__ __launch_bounds__(256) void prep_kv(const float* __restrict__ F,
                                               unsigned short* __restrict__ Khi,
                                               unsigned short* __restrict__ Vt) {
    __shared__ unsigned short ldsT[256 * 72];  // [c][q+pad], 16B-aligned rows (144B stride)
    const int tid = threadIdx.x;
    const int w = tid >> 6, lane = tid & 63;
    const int q0 = blockIdx.x * 64;
    const int b = blockIdx.y;
    const size_t bq = (size_t)b * 4096;

    for (int r = 0; r < 16; ++r) {
        const int qloc = w * 16 + r;
        const int q = q0 + qloc;
        const float4 f = *(const float4*)(F + ((bq + q) << 8) + lane * 4);
        float v0 = f.x + EPSV, v1 = f.y + EPSV, v2 = f.z + EPSV, v3 = f.w + EPSV;
        float ss = v0 * v0 + v1 * v1 + v2 * v2 + v3 * v3;
        #pragma unroll
        for (int m = 1; m <= 32; m <<= 1) ss += __shfl_xor(ss, m);
        const float inv = 1.0f / sqrtf(ss);
        const unsigned short k0 = f2bf(v0 * inv), k1 = f2bf(v1 * inv);
        const unsigned short k2 = f2bf(v2 * inv), k3 = f2bf(v3 * inv);
        ushort4 kk; kk.x = k0; kk.y = k1; kk.z = k2; kk.w = k3;
        *(ushort4*)(Khi + ((bq + q) << 8) + lane * 4) = kk;
        ldsT[(lane * 4 + 0) * 72 + qloc] = k0;
        ldsT[(lane * 4 + 1) * 72 + qloc] = k1;
        ldsT[(lane * 4 + 2) * 72 + qloc] = k2;
        ldsT[(lane * 4 + 3) * 72 + qloc] = k3;
    }
    __syncthreads();
    // Vt[b][c][q0..q0+63], one c-row per thread
    #pragma unroll
    for (int j = 0; j < 8; ++j) {
        *(uint4*)(Vt + (((size_t)b * 256 + tid) << 12) + q0 + j * 8) =
            *(const uint4*)((const char*)ldsT + tid * 144 + j * 16);
    }
}

// ---------------- prep 2: G = pool3x3(F) * 9/cnt (TF SAME semantics), bf16 ----------------
// grid (4096 spatial, 4 batch), 256 threads (one channel each).
__global__ __launch_bounds__(256) void prep_g(const float* __restrict__ F,
                                              unsigned short* __restrict__ G) {
    const int c = threadIdx.x;
    const int bx = blockIdx.x;
    const int i = bx >> 6, j = bx & 63;
    const int b = blockIdx.y;
    const size_t bq = (size_t)b * 4096;
    const int i0 = i > 0 ? i - 1 : 0, i1 = i < 63 ? i + 1 : 63;
    const int j0 = j > 0 ? j - 1 : 0, j1 = j < 63 ? j + 1 : 63;
    float sum = 0.f;
    for (int ii = i0; ii <= i1; ++ii)
        for (int jj = j0; jj <= j1; ++jj)
            sum += F[((bq + ii * 64 + jj) << 8) + c];
    const float scale = 9.0f / (float)((i1 - i0 + 1) * (j1 - j0 + 1));
    G[((bq + i * 64 + j) << 8) + c] = f2bf(sum * scale);
}

// ---------------- main fused attention ----------------
// grid (16 p-blocks, 4 q-splits, 4 batch), 256 threads (4 waves).
// Block: 256 p rows (wave w owns rows w*64..w*64+63), q-range = split*1024..+1024 in 16 tiles of 64.
// Per q-tile: stage K tile [64q][256c] and Vt tile [256c][64q] in LDS (XOR bank swizzle),
// S = G@K^T via mfma (A frags from global, L2-hot), exp -> l accum + bf16 att via per-wave LDS
// bounce (C-layout -> A-layout transpose), O += att@V via mfma into 256 f32 accumulators.
template <int ATOMIC>
__global__ __launch_bounds__(256, 1) void attn_main(
        const unsigned short* __restrict__ Khi, const unsigned short* __restrict__ Vt,
        const unsigned short* __restrict__ G, float* __restrict__ wsl,
        float* __restrict__ dOut, float* __restrict__ wsO) {
    __shared__ unsigned short ldsK[64 * 256];   // 32KB, row stride 512B, swizzled
    __shared__ unsigned short ldsV[256 * 64];   // 32KB, row stride 128B, swizzled
    __shared__ unsigned short ldsA[4 * 64 * 72];// 36KB, per-wave att bounce, padded rows (144B)
    const int tid = threadIdx.x;
    const int w = tid >> 6, lane = tid & 63;
    const int l15 = lane & 15, g4 = lane >> 4;
    const int pb = blockIdx.x, split = blockIdx.y, b = blockIdx.z;
    const int pw = pb * 256 + w * 64;
    const size_t bq = (size_t)b * 4096;

    f32x4 o[4][16];
    float lacc[4][4];
    #pragma unroll
    for (int rt = 0; rt < 4; ++rt) {
        #pragma unroll
        for (int c16 = 0; c16 < 16; ++c16) o[rt][c16] = f32x4{0.f, 0.f, 0.f, 0.f};
        #pragma unroll
        for (int r = 0; r < 4; ++r) lacc[rt][r] = 0.f;
    }
    char* ldsAw = (char*)ldsA + w * 9216;

    #pragma unroll 1
    for (int t = 0; t < 16; ++t) {
        const int q0 = split * 1024 + t * 64;
        __syncthreads();  // protect LDS from previous iteration's readers
        // stage K tile (2048 x 16B granules)
        #pragma unroll
        for (int it = 0; it < 8; ++it) {
            const int g = it * 256 + tid;
            const int row = g >> 5, o16 = g & 31;
            uint4 v = *(const uint4*)(Khi + ((bq + q0 + row) << 8) + (o16 << 3));
            *(uint4*)((char*)ldsK + (row << 9) + ((o16 << 4) ^ ((row & 7) << 4))) = v;
        }
        // stage Vt tile
        #pragma unroll
        for (int it = 0; it < 8; ++it) {
            const int g = it * 256 + tid;
            const int row = g >> 3, o16 = g & 7;
            uint4 v = *(const uint4*)(Vt + (((size_t)b * 256 + row) << 12) + q0 + (o16 << 3));
            *(uint4*)((char*)ldsV + (row << 7) + ((o16 << 4) ^ ((row & 7) << 4))) = v;
        }
        __syncthreads();

        // ---- GEMM1: S[64p x 64q] (this wave) ----
        f32x4 s[4][4];
        #pragma unroll
        for (int rt = 0; rt < 4; ++rt)
            #pragma unroll
            for (int ct = 0; ct < 4; ++ct) s[rt][ct] = f32x4{0.f, 0.f, 0.f, 0.f};
        #pragma unroll
        for (int kg = 0; kg < 8; ++kg) {
            bf16x8 a[4];
            #pragma unroll
            for (int rt = 0; rt < 4; ++rt)
                a[rt] = *(const bf16x8*)(G + ((bq + pw + rt * 16 + l15) << 8) + (kg << 5) + (g4 << 3));
            #pragma unroll
            for (int ct = 0; ct < 4; ++ct) {
                const int qr = ct * 16 + l15;
                bf16x8 bk = *(const bf16x8*)((char*)ldsK + (qr << 9) +
                                (((kg << 6) + (g4 << 4)) ^ ((qr & 7) << 4)));
                #pragma unroll
                for (int rt = 0; rt < 4; ++rt) s[rt][ct] = mfma16(a[rt], bk, s[rt][ct]);
            }
        }

        // ---- exp + l accumulation + att -> LDS (bf16) ----
        // C/D layout: row = g4*4+reg (within 16), col = l15.
        #pragma unroll
        for (int rt = 0; rt < 4; ++rt)
            #pragma unroll
            for (int ct = 0; ct < 4; ++ct)
                #pragma unroll
                for (int r = 0; r < 4; ++r) {
                    const float e = __expf(s[rt][ct][r]);
                    lacc[rt][r] += e;
                    const int plocal = rt * 16 + g4 * 4 + r;
                    *(unsigned short*)(ldsAw + (plocal * 72 + ct * 16 + l15) * 2) = f2bf(e);
                }
        __syncthreads();

        // ---- GEMM2: O += att @ V ----
        #pragma unroll
        for (int kq = 0; kq < 2; ++kq) {
            bf16x8 a2[4];
            #pragma unroll
            for (int rt = 0; rt < 4; ++rt)
                a2[rt] = *(const bf16x8*)(ldsAw + (rt * 16 + l15) * 144 + (kq << 6) + (g4 << 4));
            #pragma unroll
            for (int c16 = 0; c16 < 16; ++c16) {
                const int cr = c16 * 16 + l15;
                bf16x8 bv = *(const bf16x8*)((char*)ldsV + (cr << 7) +
                                (((kq << 6) + (g4 << 4)) ^ ((cr & 7) << 4)));
                #pragma unroll
                for (int rt = 0; rt < 4; ++rt) o[rt][c16] = mfma16(a2[rt], bv, o[rt][c16]);
            }
        }
    }

    // ---- epilogue: reduce l across the 16 columns (lanes sharing g4) ----
    #pragma unroll
    for (int rt = 0; rt < 4; ++rt)
        #pragma unroll
        for (int r = 0; r < 4; ++r) {
            float v = lacc[rt][r];
            #pragma unroll
            for (int m = 1; m <= 8; m <<= 1) v += __shfl_xor(v, m);
            lacc[rt][r] = v;
        }
    if (l15 == 0) {
        #pragma unroll
        for (int rt = 0; rt < 4; ++rt)
            #pragma unroll
            for (int r = 0; r < 4; ++r)
                wsl[(size_t)split * 16384 + bq + pw + rt * 16 + g4 * 4 + r] = lacc[rt][r];
    }
    float* dst = (ATOMIC || split == 0) ? dOut : (wsO + (size_t)(split - 1) * 4194304);
    #pragma unroll
    for (int rt = 0; rt < 4; ++rt)
        #pragma unroll
        for (int c16 = 0; c16 < 16; ++c16)
            #pragma unroll
            for (int r = 0; r < 4; ++r) {
                const size_t idx = ((bq + pw + rt * 16 + g4 * 4 + r) << 8) + c16 * 16 + l15;
                if (ATOMIC) atomicAdd(&dst[idx], o[rt][c16][r]);
                else dst[idx] = o[rt][c16][r];
            }
}

// ---------------- finalize: sum q-split partials, divide by l ----------------
__global__ __launch_bounds__(256) void reduce_fin(float* __restrict__ dOut,
                                                  const float* __restrict__ wsO,
                                                  const float* __restrict__ wsl) {
    const int i4 = blockIdx.x * 256 + threadIdx.x;  // float4 index
    const int row = i4 >> 6;
    const float l = wsl[row] + wsl[16384 + row] + wsl[32768 + row] + wsl[49152 + row];
    const float inv = 1.0f / l;
    float4 v = ((const float4*)dOut)[i4];
    const float4 a = ((const float4*)wsO)[i4];
    const float4 b = ((const float4*)(wsO + 4194304))[i4];
    const float4 c = ((const float4*)(wsO + 8388608))[i4];
    v.x = (v.x + a.x + b.x + c.x) * inv;
    v.y = (v.y + a.y + b.y + c.y) * inv;
    v.z = (v.z + a.z + b.z + c.z) * inv;
    v.w = (v.w + a.w + b.w + c.w) * inv;
    ((float4*)dOut)[i4] = v;
}

__global__ __launch_bounds__(256) void divide_fin(float* __restrict__ dOut,
                                                  const float* __restrict__ wsl) {
    const int i4 = blockIdx.x * 256 + threadIdx.x;
    const int row = i4 >> 6;
    const float l = wsl[row] + wsl[16384 + row] + wsl[32768 + row] + wsl[49152 + row];
    const float inv = 1.0f / l;
    float4 v = ((const float4*)dOut)[i4];
    v.x *= inv; v.y *= inv; v.z *= inv; v.w *= inv;
    ((float4*)dOut)[i4] = v;
}

extern "C" void kernel_launch(void* const* d_in, const int* in_sizes, int n_in,
                              void* d_out, int out_size, void* d_ws, size_t ws_size,
                              hipStream_t stream) {
    const float* F = (const float*)d_in[0];
    // d_in[1] (masks) has no effect on the output (only stored as state in the reference).
    float* out = (float*)d_out;
    char* ws = (char*)d_ws;

    // ws layout: Khi bf16 [4][4096][256] @0 (8MB) | Vt bf16 [4][256][4096] @8MB |
    //            G bf16 [4][4096][256] @16MB | wsl f32 [4][16384] @24MB (256KB) |
    //            wsO f32 3x[4][4096][256] @24.25MB (48MB)
    unsigned short* Khi = (unsigned short*)ws;
    unsigned short* Vt = Khi + 4194304;
    unsigned short* G = Vt + 4194304;
    float* wsl = (float*)(ws + 25165824);
    float* wsO = (float*)(ws + 25165824 + 262144);
    const size_t needA = 25165824u + 262144u + 3u * 16777216u;

    prep_kv<<<dim3(64, 4), 256, 0, stream>>>(F, Khi, Vt);
    prep_g<<<dim3(4096, 4), 256, 0, stream>>>(F, G);

    if (ws_size >= needA) {
        attn_main<0><<<dim3(16, 4, 4), 256, 0, stream>>>(Khi, Vt, G, wsl, out, wsO);
        reduce_fin<<<4096, 256, 0, stream>>>(out, wsO, wsl);
    } else {
        hipMemsetAsync(out, 0, 16777216, stream);
        attn_main<1><<<dim3(16, 4, 4), 256, 0, stream>>>(Khi, Vt, G, wsl, out, nullptr);
        divide_fin<<<4096, 256, 0, stream>>>(out, wsl);
    }
}

// Round 2
// 298.337 us; speedup vs baseline: 1.6930x; 1.6930x over previous
//
#include <hip/hip_runtime.h>

// KnowledgeConsistentAttention: out = softmax_q( pool3x3(F) . K^T ) . K,  K = normalize(F+eps)
// pool3x3 acts only on the p index of S = F.K^T, so pool(F.K^T) = pool(F).K^T.
// => flash-attention-style fused kernel with Q=G=pool3x3(F), K=V=normalize(F+eps).
// |S| <= ~70 so exp(S) fits fp32 -> no max subtraction; accumulate unnormalized O and row-sum l,
// divide at the end. bf16 MFMA (16x16x32) throughout; fp32 accumulation.
//
// R2: G A-frags preloaded to registers (no global loads in K-loop); 32 p-rows/wave;
// LDS = 80KB exactly -> 2 blocks/CU (8 waves/CU); async global_load_lds staging with
// inverse-swizzled source + linear LDS dest; XCD-aware block swizzle.

#define EPSV 1e-7f

typedef __bf16 bf16x8 __attribute__((ext_vector_type(8)));
typedef float f32x4 __attribute__((ext_vector_type(4)));

__device__ __forceinline__ unsigned short f2bf(float f) {
    union { float f; unsigned int u; } x; x.f = f;
    unsigned int r = x.u + 0x7FFFu + ((x.u >> 16) & 1u);
    return (unsigned short)(r >> 16);
}

__device__ __forceinline__ f32x4 mfma16(bf16x8 a, bf16x8 b, f32x4 c) {
    return __builtin_amdgcn_mfma_f32_16x16x32_bf16(a, b, c, 0, 0, 0);
}

__device__ __forceinline__ void gload_lds16(const void* g, void* l) {
    __builtin_amdgcn_global_load_lds((const __attribute__((address_space(1))) void*)g,
                                     (__attribute__((address_space(3))) void*)l, 16, 0, 0);
}

// ---------------- prep 1: K_hi (bf16 normalized rows) + Vt (transposed copy) ----------------
__global__ __launch_bounds__(256) void prep_kv(const float* __restrict__ F,
                                               unsigned short* __restrict__ Khi,
                                               unsigned short* __restrict__ Vt) {
    __shared__ unsigned short ldsT[256 * 72];
    const int tid = threadIdx.x;
    const int w = tid >> 6, lane = tid & 63;
    const int q0 = blockIdx.x * 64;
    const int b = blockIdx.y;
    const size_t bq = (size_t)b * 4096;

    for (int r = 0; r < 16; ++r) {
        const int qloc = w * 16 + r;
        const int q = q0 + qloc;
        const float4 f = *(const float4*)(F + ((bq + q) << 8) + lane * 4);
        float v0 = f.x + EPSV, v1 = f.y + EPSV, v2 = f.z + EPSV, v3 = f.w + EPSV;
        float ss = v0 * v0 + v1 * v1 + v2 * v2 + v3 * v3;
        #pragma unroll
        for (int m = 1; m <= 32; m <<= 1) ss += __shfl_xor(ss, m);
        const float inv = 1.0f / sqrtf(ss);
        const unsigned short k0 = f2bf(v0 * inv), k1 = f2bf(v1 * inv);
        const unsigned short k2 = f2bf(v2 * inv), k3 = f2bf(v3 * inv);
        ushort4 kk; kk.x = k0; kk.y = k1; kk.z = k2; kk.w = k3;
        *(ushort4*)(Khi + ((bq + q) << 8) + lane * 4) = kk;
        ldsT[(lane * 4 + 0) * 72 + qloc] = k0;
        ldsT[(lane * 4 + 1) * 72 + qloc] = k1;
        ldsT[(lane * 4 + 2) * 72 + qloc] = k2;
        ldsT[(lane * 4 + 3) * 72 + qloc] = k3;
    }
    __syncthreads();
    #pragma unroll
    for (int j = 0; j < 8; ++j) {
        *(uint4*)(Vt + (((size_t)b * 256 + tid) << 12) + q0 + j * 8) =
            *(const uint4*)((const char*)ldsT + tid * 144 + j * 16);
    }
}

// ---------------- prep 2: G = pool3x3(F) * 9/cnt (TF SAME), separable, bf16 ----------------
// grid (64 rows i, 4 b), 256 threads. Vertical sums staged in LDS, then horizontal.
__global__ __launch_bounds__(256) void prep_g(const float* __restrict__ F,
                                              unsigned short* __restrict__ G) {
    __shared__ float vs[64 * 256];
    const int tid = threadIdx.x;
    const int i = blockIdx.x, b = blockIdx.y;
    const size_t bq = (size_t)b * 4096;
    const int i0 = i > 0 ? i - 1 : 0, i1 = i < 63 ? i + 1 : 63;
    #pragma unroll
    for (int k2 = 0; k2 < 16; ++k2) {
        const int cell = k2 * 256 + tid;
        const int j = cell >> 6, c4 = (cell & 63) << 2;
        float4 acc = {0.f, 0.f, 0.f, 0.f};
        for (int ii = i0; ii <= i1; ++ii) {
            const float4 f = *(const float4*)(F + ((bq + ii * 64 + j) << 8) + c4);
            acc.x += f.x; acc.y += f.y; acc.z += f.z; acc.w += f.w;
        }
        *(float4*)(vs + j * 256 + c4) = acc;
    }
    __syncthreads();
    const float ri = (float)(i1 - i0 + 1);
    #pragma unroll
    for (int k2 = 0; k2 < 16; ++k2) {
        const int cell = k2 * 256 + tid;
        const int j = cell >> 6, c4 = (cell & 63) << 2;
        const int j0 = j > 0 ? j - 1 : 0, j1 = j < 63 ? j + 1 : 63;
        float4 s = {0.f, 0.f, 0.f, 0.f};
        for (int jj = j0; jj <= j1; ++jj) {
            const float4 v = *(const float4*)(vs + jj * 256 + c4);
            s.x += v.x; s.y += v.y; s.z += v.z; s.w += v.w;
        }
        const float scale = 9.0f / (ri * (float)(j1 - j0 + 1));
        ushort4 gv; gv.x = f2bf(s.x * scale); gv.y = f2bf(s.y * scale);
        gv.z = f2bf(s.z * scale); gv.w = f2bf(s.w * scale);
        *(ushort4*)(G + ((bq + i * 64 + j) << 8) + c4) = gv;
    }
}

// ---------------- main fused attention ----------------
// grid: 512 blocks (XCD-swizzled -> pb[32] x split[4] x b[4]), 256 threads (4 waves).
// Wave owns 32 p-rows (block 128). q-range = split*1024..+1024 in 16 tiles of 64.
// Per tile: K[64q][256c] + Vt[256c][64q] staged async via global_load_lds (XOR-swizzled via
// pre-swizzled source); S = G@K^T (A-frags preloaded in regs); exp -> P to per-wave swizzled
// LDS; O += P@V. O in 128 f32 accumulators.
template <int ATOMIC>
__global__ __launch_bounds__(256, 2) void attn_main(
        const unsigned short* __restrict__ Khi, const unsigned short* __restrict__ Vt,
        const unsigned short* __restrict__ G, float* __restrict__ wsl,
        float* __restrict__ dOut, float* __restrict__ wsO) {
    __shared__ unsigned short ldsK[64 * 256];   // 32KB, row 512B, swizzled granules
    __shared__ unsigned short ldsV[256 * 64];   // 32KB, row 128B, swizzled granules
    __shared__ unsigned short ldsP[4 * 32 * 64];// 16KB, per-wave P bounce, XOR-swizzled
    const int tid = threadIdx.x;
    const int w = tid >> 6, lane = tid & 63;
    const int l15 = lane & 15, g4 = lane >> 4;

    // XCD-aware decomposition: all 32 pb of a (split,b) group land on one XCD
    const int bid = blockIdx.x;
    const int u = bid & 7, v = bid >> 3;
    const int group = u * 2 + (v >> 5);
    const int pb = v & 31;
    const int split = group >> 2, b = group & 3;

    const int pw = pb * 128 + w * 32;
    const size_t bq = (size_t)b * 4096;

    // ---- preload G A-frags: 32 rows x 256 k per wave -> 64 VGPRs ----
    bf16x8 a[2][8];
    #pragma unroll
    for (int rt = 0; rt < 2; ++rt)
        #pragma unroll
        for (int kg = 0; kg < 8; ++kg)
            a[rt][kg] = *(const bf16x8*)(G + ((bq + pw + rt * 16 + l15) << 8) + (kg << 5) + (g4 << 3));

    f32x4 o[2][16];
    float lacc[2][4];
    #pragma unroll
    for (int rt = 0; rt < 2; ++rt) {
        #pragma unroll
        for (int c16 = 0; c16 < 16; ++c16) o[rt][c16] = f32x4{0.f, 0.f, 0.f, 0.f};
        #pragma unroll
        for (int r = 0; r < 4; ++r) lacc[rt][r] = 0.f;
    }
    char* ldsPw = (char*)ldsP + w * 4096;

    // ---- per-lane staging source bases (swizzle folded into source address) ----
    const int krow = w * 2 + (lane >> 5);
    const char* kSrc = (const char*)Khi + (size_t)(bq + split * 1024 + krow) * 512
                     + (((lane & 31) ^ (krow & 7)) << 4);
    const int vrow = w * 8 + (lane >> 3);
    const char* vSrc = (const char*)Vt + ((size_t)b * 256 + vrow) * 8192 + (size_t)split * 2048
                     + (((lane & 7) ^ (vrow & 7)) << 4);
    char* kDst = (char*)ldsK + w * 1024;
    char* vDst = (char*)ldsV + w * 1024;

    // prologue: stage tile 0
    #pragma unroll
    for (int it = 0; it < 8; ++it) gload_lds16(kSrc + it * 4096, kDst + it * 4096);
    #pragma unroll
    for (int it = 0; it < 8; ++it) gload_lds16(vSrc + it * 262144, vDst + it * 4096);

    #pragma unroll 1
    for (int t = 0; t < 16; ++t) {
        __syncthreads();  // K(t), V(t) landed & visible

        // ---- GEMM1: S[32p x 64q] ----
        f32x4 s[2][4];
        #pragma unroll
        for (int rt = 0; rt < 2; ++rt)
            #pragma unroll
            for (int ct = 0; ct < 4; ++ct) s[rt][ct] = f32x4{0.f, 0.f, 0.f, 0.f};
        #pragma unroll
        for (int kg = 0; kg < 8; ++kg) {
            #pragma unroll
            for (int ct = 0; ct < 4; ++ct) {
                const int qr = ct * 16 + l15;
                const bf16x8 bk = *(const bf16x8*)((char*)ldsK + (qr << 9) +
                                    ((((kg << 6) + (g4 << 4))) ^ ((qr & 7) << 4)));
                s[0][ct] = mfma16(a[0][kg], bk, s[0][ct]);
                s[1][ct] = mfma16(a[1][kg], bk, s[1][ct]);
            }
        }
        __syncthreads();  // all waves done reading K(t)

        // stage K(t+1) async (lands during exp + GEMM2)
        if (t < 15) {
            const char* ks = kSrc + (size_t)(t + 1) * 32768;
            #pragma unroll
            for (int it = 0; it < 8; ++it) gload_lds16(ks + it * 4096, kDst + it * 4096);
        }

        // ---- exp + l accum + P -> per-wave swizzled LDS (bf16) ----
        #pragma unroll
        for (int rt = 0; rt < 2; ++rt)
            #pragma unroll
            for (int ct = 0; ct < 4; ++ct)
                #pragma unroll
                for (int r = 0; r < 4; ++r) {
                    const float e = __expf(s[rt][ct][r]);
                    lacc[rt][r] += e;
                    const int p = rt * 16 + g4 * 4 + r;
                    *(unsigned short*)(ldsPw + (p << 7) +
                        (((ct << 5) + (l15 << 1)) ^ ((p & 7) << 4))) = f2bf(e);
                }

        // ---- GEMM2: O += P @ V ----
        #pragma unroll
        for (int kq = 0; kq < 2; ++kq) {
            bf16x8 a2[2];
            #pragma unroll
            for (int rt = 0; rt < 2; ++rt) {
                const int p = rt * 16 + l15;
                a2[rt] = *(const bf16x8*)(ldsPw + (p << 7) +
                            ((((kq << 6) + (g4 << 4))) ^ ((p & 7) << 4)));
            }
            #pragma unroll
            for (int c16 = 0; c16 < 16; ++c16) {
                const int cr = c16 * 16 + l15;
                const bf16x8 bv = *(const bf16x8*)((char*)ldsV + (cr << 7) +
                                    ((((kq << 6) + (g4 << 4))) ^ ((cr & 7) << 4)));
                o[0][c16] = mfma16(a2[0], bv, o[0][c16]);
                o[1][c16] = mfma16(a2[1], bv, o[1][c16]);
            }
        }
        __syncthreads();  // all waves done reading V(t)

        // stage V(t+1) async
        if (t < 15) {
            const char* vsrc = vSrc + (t + 1) * 128;
            #pragma unroll
            for (int it = 0; it < 8; ++it) gload_lds16(vsrc + it * 262144, vDst + it * 4096);
        }
    }

    // ---- epilogue: reduce l across 16 columns (lanes sharing g4) ----
    #pragma unroll
    for (int rt = 0; rt < 2; ++rt)
        #pragma unroll
        for (int r = 0; r < 4; ++r) {
            float vsum = lacc[rt][r];
            #pragma unroll
            for (int m = 1; m <= 8; m <<= 1) vsum += __shfl_xor(vsum, m);
            lacc[rt][r] = vsum;
        }
    if (l15 == 0) {
        #pragma unroll
        for (int rt = 0; rt < 2; ++rt)
            #pragma unroll
            for (int r = 0; r < 4; ++r)
                wsl[(size_t)split * 16384 + bq + pw + rt * 16 + g4 * 4 + r] = lacc[rt][r];
    }
    float* dst = (ATOMIC || split == 0) ? dOut : (wsO + (size_t)(split - 1) * 4194304);
    #pragma unroll
    for (int rt = 0; rt < 2; ++rt)
        #pragma unroll
        for (int c16 = 0; c16 < 16; ++c16)
            #pragma unroll
            for (int r = 0; r < 4; ++r) {
                const size_t idx = ((bq + pw + rt * 16 + g4 * 4 + r) << 8) + c16 * 16 + l15;
                if (ATOMIC) atomicAdd(&dst[idx], o[rt][c16][r]);
                else dst[idx] = o[rt][c16][r];
            }
}

// ---------------- finalize: sum q-split partials, divide by l ----------------
__global__ __launch_bounds__(256) void reduce_fin(float* __restrict__ dOut,
                                                  const float* __restrict__ wsO,
                                                  const float* __restrict__ wsl) {
    const int i4 = blockIdx.x * 256 + threadIdx.x;
    const int row = i4 >> 6;
    const float l = wsl[row] + wsl[16384 + row] + wsl[32768 + row] + wsl[49152 + row];
    const float inv = 1.0f / l;
    float4 v = ((const float4*)dOut)[i4];
    const float4 a = ((const float4*)wsO)[i4];
    const float4 b = ((const float4*)(wsO + 4194304))[i4];
    const float4 c = ((const float4*)(wsO + 8388608))[i4];
    v.x = (v.x + a.x + b.x + c.x) * inv;
    v.y = (v.y + a.y + b.y + c.y) * inv;
    v.z = (v.z + a.z + b.z + c.z) * inv;
    v.w = (v.w + a.w + b.w + c.w) * inv;
    ((float4*)dOut)[i4] = v;
}

__global__ __launch_bounds__(256) void divide_fin(float* __restrict__ dOut,
                                                  const float* __restrict__ wsl) {
    const int i4 = blockIdx.x * 256 + threadIdx.x;
    const int row = i4 >> 6;
    const float l = wsl[row] + wsl[16384 + row] + wsl[32768 + row] + wsl[49152 + row];
    const float inv = 1.0f / l;
    float4 v = ((const float4*)dOut)[i4];
    v.x *= inv; v.y *= inv; v.z *= inv; v.w *= inv;
    ((float4*)dOut)[i4] = v;
}

extern "C" void kernel_launch(void* const* d_in, const int* in_sizes, int n_in,
                              void* d_out, int out_size, void* d_ws, size_t ws_size,
                              hipStream_t stream) {
    const float* F = (const float*)d_in[0];
    // d_in[1] (masks) has no effect on the output.
    float* out = (float*)d_out;
    char* ws = (char*)d_ws;

    // ws layout: Khi bf16 [4][4096][256] @0 (8MB) | Vt bf16 [4][256][4096] @8MB |
    //            G bf16 [4][4096][256] @16MB | wsl f32 [4][16384] @24MB (256KB) |
    //            wsO f32 3x[4][4096][256] @24.25MB (48MB)
    unsigned short* Khi = (unsigned short*)ws;
    unsigned short* Vt = Khi + 4194304;
    unsigned short* G = Vt + 4194304;
    float* wsl = (float*)(ws + 25165824);
    float* wsO = (float*)(ws + 25165824 + 262144);
    const size_t needA = 25165824u + 262144u + 3u * 16777216u;

    prep_kv<<<dim3(64, 4), 256, 0, stream>>>(F, Khi, Vt);
    prep_g<<<dim3(64, 4), 256, 0, stream>>>(F, G);

    if (ws_size >= needA) {
        attn_main<0><<<dim3(512), 256, 0, stream>>>(Khi, Vt, G, wsl, out, wsO);
        reduce_fin<<<4096, 256, 0, stream>>>(out, wsO, wsl);
    } else {
        hipMemsetAsync(out, 0, 16777216, stream);
        attn_main<1><<<dim3(512), 256, 0, stream>>>(Khi, Vt, G, wsl, out, nullptr);
        divide_fin<<<4096, 256, 0, stream>>>(out, wsl);
    }
}

// Round 3
// 164.505 us; speedup vs baseline: 3.0703x; 1.8135x over previous
//
#include <hip/hip_runtime.h>

// KnowledgeConsistentAttention: out = softmax_q( pool3x3(F) . K^T ) . K,  K = normalize(F+eps)
// pool3x3 acts only on the p index of S = F.K^T => flash-style fused kernel with
// Q=G=pool3x3(F), K=V=normalize(F+eps). exp(S) fits fp32 -> no max subtraction.
//
// R3: double-buffered K/V tiles (q-tile 32) with ONE __syncthreads per tile; stage(t+1)
// issued BEFORE compute(t) so the barrier's vmcnt(0) drain is ~free (T3 2-phase recipe).
// GEMM2 computes O^T (swapped mfma operands) -> float4 coalesced epilogue stores.

#define EPSV 1e-7f

typedef __bf16 bf16x8 __attribute__((ext_vector_type(8)));
typedef float f32x4 __attribute__((ext_vector_type(4)));

__device__ __forceinline__ unsigned short f2bf(float f) {
    union { float f; unsigned int u; } x; x.f = f;
    unsigned int r = x.u + 0x7FFFu + ((x.u >> 16) & 1u);
    return (unsigned short)(r >> 16);
}

__device__ __forceinline__ f32x4 mfma16(bf16x8 a, bf16x8 b, f32x4 c) {
    return __builtin_amdgcn_mfma_f32_16x16x32_bf16(a, b, c, 0, 0, 0);
}

__device__ __forceinline__ void gload_lds16(const void* g, void* l) {
    __builtin_amdgcn_global_load_lds((const __attribute__((address_space(1))) void*)g,
                                     (__attribute__((address_space(3))) void*)l, 16, 0, 0);
}

// ---------------- prep 1: K_hi (bf16 normalized rows) + Vt (transposed copy) ----------------
__global__ __launch_bounds__(256) void prep_kv(const float* __restrict__ F,
                                               unsigned short* __restrict__ Khi,
                                               unsigned short* __restrict__ Vt) {
    __shared__ unsigned short ldsT[256 * 72];
    const int tid = threadIdx.x;
    const int w = tid >> 6, lane = tid & 63;
    const int q0 = blockIdx.x * 64;
    const int b = blockIdx.y;
    const size_t bq = (size_t)b * 4096;

    for (int r = 0; r < 16; ++r) {
        const int qloc = w * 16 + r;
        const int q = q0 + qloc;
        const float4 f = *(const float4*)(F + ((bq + q) << 8) + lane * 4);
        float v0 = f.x + EPSV, v1 = f.y + EPSV, v2 = f.z + EPSV, v3 = f.w + EPSV;
        float ss = v0 * v0 + v1 * v1 + v2 * v2 + v3 * v3;
        #pragma unroll
        for (int m = 1; m <= 32; m <<= 1) ss += __shfl_xor(ss, m);
        const float inv = 1.0f / sqrtf(ss);
        const unsigned short k0 = f2bf(v0 * inv), k1 = f2bf(v1 * inv);
        const unsigned short k2 = f2bf(v2 * inv), k3 = f2bf(v3 * inv);
        ushort4 kk; kk.x = k0; kk.y = k1; kk.z = k2; kk.w = k3;
        *(ushort4*)(Khi + ((bq + q) << 8) + lane * 4) = kk;
        ldsT[(lane * 4 + 0) * 72 + qloc] = k0;
        ldsT[(lane * 4 + 1) * 72 + qloc] = k1;
        ldsT[(lane * 4 + 2) * 72 + qloc] = k2;
        ldsT[(lane * 4 + 3) * 72 + qloc] = k3;
    }
    __syncthreads();
    #pragma unroll
    for (int j = 0; j < 8; ++j) {
        *(uint4*)(Vt + (((size_t)b * 256 + tid) << 12) + q0 + j * 8) =
            *(const uint4*)((const char*)ldsT + tid * 144 + j * 16);
    }
}

// ---------------- prep 2: G = pool3x3(F) * 9/cnt (TF SAME), separable, bf16 ----------------
__global__ __launch_bounds__(256) void prep_g(const float* __restrict__ F,
                                              unsigned short* __restrict__ G) {
    __shared__ float vs[64 * 256];
    const int tid = threadIdx.x;
    const int i = blockIdx.x, b = blockIdx.y;
    const size_t bq = (size_t)b * 4096;
    const int i0 = i > 0 ? i - 1 : 0, i1 = i < 63 ? i + 1 : 63;
    #pragma unroll
    for (int k2 = 0; k2 < 16; ++k2) {
        const int cell = k2 * 256 + tid;
        const int j = cell >> 6, c4 = (cell & 63) << 2;
        float4 acc = {0.f, 0.f, 0.f, 0.f};
        for (int ii = i0; ii <= i1; ++ii) {
            const float4 f = *(const float4*)(F + ((bq + ii * 64 + j) << 8) + c4);
            acc.x += f.x; acc.y += f.y; acc.z += f.z; acc.w += f.w;
        }
        *(float4*)(vs + j * 256 + c4) = acc;
    }
    __syncthreads();
    const float ri = (float)(i1 - i0 + 1);
    #pragma unroll
    for (int k2 = 0; k2 < 16; ++k2) {
        const int cell = k2 * 256 + tid;
        const int j = cell >> 6, c4 = (cell & 63) << 2;
        const int j0 = j > 0 ? j - 1 : 0, j1 = j < 63 ? j + 1 : 63;
        float4 s = {0.f, 0.f, 0.f, 0.f};
        for (int jj = j0; jj <= j1; ++jj) {
            const float4 v = *(const float4*)(vs + jj * 256 + c4);
            s.x += v.x; s.y += v.y; s.z += v.z; s.w += v.w;
        }
        const float scale = 9.0f / (ri * (float)(j1 - j0 + 1));
        ushort4 gv; gv.x = f2bf(s.x * scale); gv.y = f2bf(s.y * scale);
        gv.z = f2bf(s.z * scale); gv.w = f2bf(s.w * scale);
        *(ushort4*)(G + ((bq + i * 64 + j) << 8) + c4) = gv;
    }
}

// ---------------- main fused attention ----------------
// grid: 512 blocks (XCD-swizzled -> pb[32] x split[4] x b[4]), 256 threads (4 waves).
// Wave owns 32 p-rows. q-split = 1024 q's in 32 tiles of 32, double-buffered K/V in LDS.
// Per tile: issue stage(t+1) -> GEMM1 (A=G regs, B=K lds) -> exp/P bounce -> GEMM2 (O^T:
// A=V lds, B=P lds) -> one __syncthreads (drains t+1 loads issued a full tile ago).
template <int ATOMIC>
__global__ __launch_bounds__(256, 2) void attn_main(
        const unsigned short* __restrict__ Khi, const unsigned short* __restrict__ Vt,
        const unsigned short* __restrict__ G, float* __restrict__ wsl,
        float* __restrict__ dOut, float* __restrict__ wsO) {
    __shared__ unsigned short ldsK[2][32 * 256];  // 2 x 16KB, row 512B, granule-XOR swizzle
    __shared__ unsigned short ldsV[2][128 * 64];  // 2 x 16KB, paired c-rows: R=c>>1, 128B rows
    __shared__ unsigned short ldsP[4][32 * 40];   // 10KB, per-wave P bounce, 80B padded rows
    const int tid = threadIdx.x;
    const int w = tid >> 6, lane = tid & 63;
    const int l15 = lane & 15, g4 = lane >> 4;

    // XCD-aware decomposition: all 32 pb of a (split,b) group land on one XCD
    const int bid = blockIdx.x;
    const int u = bid & 7, v = bid >> 3;
    const int group = u * 2 + (v >> 5);
    const int pb = v & 31;
    const int split = group >> 2, b = group & 3;

    const int pw = pb * 128 + w * 32;
    const size_t bq = (size_t)b * 4096;

    // ---- staging: per-thread source mapping (inverse of read-side XOR swizzle) ----
    const char* KhiB = (const char*)Khi + ((bq + split * 1024) << 9);  // tile rows * 512B
    const char* VtB = (const char*)Vt + (((size_t)b * 256) << 13) + split * 2048;

    // prologue: stage tile 0 into buf 0
    {
        #pragma unroll
        for (int it = 0; it < 4; ++it) {
            const int gK = it * 256 + tid;
            const int row = gK >> 5, pos = gK & 31;
            gload_lds16(KhiB + row * 512 + (pos ^ (row & 7)) * 16,
                        (char*)&ldsK[0][0] + (it * 256 + w * 64) * 16);
        }
        #pragma unroll
        for (int it = 0; it < 4; ++it) {
            const int gV = it * 256 + tid;
            const int R = gV >> 3, pos = gV & 7;
            const int tp = pos ^ (R & 7);
            gload_lds16(VtB + ((size_t)(2 * R + (tp >> 2)) << 13) + (tp & 3) * 16,
                        (char*)&ldsV[0][0] + (it * 256 + w * 64) * 16);
        }
    }

    // ---- preload G A-frags: 32 rows x 256 k per wave -> 64 VGPRs ----
    bf16x8 a[2][8];
    #pragma unroll
    for (int rt = 0; rt < 2; ++rt)
        #pragma unroll
        for (int kg = 0; kg < 8; ++kg)
            a[rt][kg] = *(const bf16x8*)(G + ((bq + pw + rt * 16 + l15) << 8) + (kg << 5) + (g4 << 3));

    f32x4 o[2][16];
    float lacc[2][4];
    #pragma unroll
    for (int rt = 0; rt < 2; ++rt) {
        #pragma unroll
        for (int c16 = 0; c16 < 16; ++c16) o[rt][c16] = f32x4{0.f, 0.f, 0.f, 0.f};
        #pragma unroll
        for (int r = 0; r < 4; ++r) lacc[rt][r] = 0.f;
    }
    unsigned short* Pw = &ldsP[w][0];

    __syncthreads();  // tile 0 landed

    #pragma unroll 1
    for (int t = 0; t < 32; ++t) {
        const int cur = t & 1;

        // ---- issue stage of tile t+1 into the other buffer (drained at end-of-iter sync) ----
        if (t < 31) {
            const char* ks = KhiB + (size_t)(t + 1) * 16384;
            #pragma unroll
            for (int it = 0; it < 4; ++it) {
                const int gK = it * 256 + tid;
                const int row = gK >> 5, pos = gK & 31;
                gload_lds16(ks + row * 512 + (pos ^ (row & 7)) * 16,
                            (char*)&ldsK[cur ^ 1][0] + (it * 256 + w * 64) * 16);
            }
            const char* vsrc = VtB + (t + 1) * 64;
            #pragma unroll
            for (int it = 0; it < 4; ++it) {
                const int gV = it * 256 + tid;
                const int R = gV >> 3, pos = gV & 7;
                const int tp = pos ^ (R & 7);
                gload_lds16(vsrc + ((size_t)(2 * R + (tp >> 2)) << 13) + (tp & 3) * 16,
                            (char*)&ldsV[cur ^ 1][0] + (it * 256 + w * 64) * 16);
            }
        }

        // ---- GEMM1: S[32p x 32q] ----
        f32x4 s[2][2];
        #pragma unroll
        for (int rt = 0; rt < 2; ++rt)
            #pragma unroll
            for (int ct = 0; ct < 2; ++ct) s[rt][ct] = f32x4{0.f, 0.f, 0.f, 0.f};
        __builtin_amdgcn_s_setprio(1);
        #pragma unroll
        for (int kg = 0; kg < 8; ++kg) {
            #pragma unroll
            for (int ct = 0; ct < 2; ++ct) {
                const int qr = ct * 16 + l15;
                const bf16x8 bk = *(const bf16x8*)((const char*)&ldsK[cur][0] + (qr << 9) +
                                    ((((kg << 2) + g4)) ^ (qr & 7)) * 16);
                s[0][ct] = mfma16(a[0][kg], bk, s[0][ct]);
                s[1][ct] = mfma16(a[1][kg], bk, s[1][ct]);
            }
        }
        __builtin_amdgcn_s_setprio(0);

        // ---- exp + l accum + P -> per-wave LDS (bf16), S C-layout: row=g4*4+r, col=l15 ----
        #pragma unroll
        for (int rt = 0; rt < 2; ++rt)
            #pragma unroll
            for (int ct = 0; ct < 2; ++ct)
                #pragma unroll
                for (int r = 0; r < 4; ++r) {
                    const float e = __expf(s[rt][ct][r]);
                    lacc[rt][r] += e;
                    Pw[(rt * 16 + g4 * 4 + r) * 40 + ct * 16 + l15] = f2bf(e);
                }

        // ---- GEMM2 (O^T): A = V-frag (lane=c), B = P-frag (lane=p) ----
        __builtin_amdgcn_s_setprio(1);
        bf16x8 a2[2];
        #pragma unroll
        for (int rt = 0; rt < 2; ++rt)
            a2[rt] = *(const bf16x8*)((const char*)Pw + (rt * 16 + l15) * 80 + (g4 << 4));
        #pragma unroll
        for (int c16 = 0; c16 < 16; ++c16) {
            const int cr = c16 * 16 + l15;
            const int R = cr >> 1;
            const bf16x8 bv = *(const bf16x8*)((const char*)&ldsV[cur][0] + (R << 7) +
                                ((((cr & 1) << 2) + g4) ^ (R & 7)) * 16);
            o[0][c16] = mfma16(bv, a2[0], o[0][c16]);
            o[1][c16] = mfma16(bv, a2[1], o[1][c16]);
        }
        __builtin_amdgcn_s_setprio(0);

        if (t < 31) __syncthreads();  // t+1 staged (issued one full tile ago) + buffer handoff
    }

    // ---- epilogue: reduce l across 16 columns (lanes sharing g4) ----
    #pragma unroll
    for (int rt = 0; rt < 2; ++rt)
        #pragma unroll
        for (int r = 0; r < 4; ++r) {
            float vsum = lacc[rt][r];
            #pragma unroll
            for (int m = 1; m <= 8; m <<= 1) vsum += __shfl_xor(vsum, m);
            lacc[rt][r] = vsum;
        }
    if (l15 == 0) {
        #pragma unroll
        for (int rt = 0; rt < 2; ++rt)
            #pragma unroll
            for (int r = 0; r < 4; ++r)
                wsl[(size_t)split * 16384 + bq + pw + rt * 16 + g4 * 4 + r] = lacc[rt][r];
    }

    // O^T D-layout: lane l15 = p-col, reg r = consecutive c -> float4 coalesced stores
    if (!ATOMIC) {
        float* dst = (split == 0) ? dOut : (wsO + (size_t)(split - 1) * 4194304);
        #pragma unroll
        for (int rt = 0; rt < 2; ++rt)
            #pragma unroll
            for (int c16 = 0; c16 < 16; ++c16)
                *(f32x4*)(dst + ((bq + pw + rt * 16 + l15) << 8) + c16 * 16 + (g4 << 2)) = o[rt][c16];
    } else {
        #pragma unroll
        for (int rt = 0; rt < 2; ++rt)
            #pragma unroll
            for (int c16 = 0; c16 < 16; ++c16)
                #pragma unroll
                for (int r = 0; r < 4; ++r) {
                    const size_t idx = ((bq + pw + rt * 16 + l15) << 8) + c16 * 16 + (g4 << 2) + r;
                    atomicAdd(&dOut[idx], o[rt][c16][r]);
                }
    }
}

// ---------------- finalize: sum q-split partials, divide by l ----------------
__global__ __launch_bounds__(256) void reduce_fin(float* __restrict__ dOut,
                                                  const float* __restrict__ wsO,
                                                  const float* __restrict__ wsl) {
    const int i4 = blockIdx.x * 256 + threadIdx.x;
    const int row = i4 >> 6;
    const float l = wsl[row] + wsl[16384 + row] + wsl[32768 + row] + wsl[49152 + row];
    const float inv = 1.0f / l;
    float4 v = ((const float4*)dOut)[i4];
    const float4 a = ((const float4*)wsO)[i4];
    const float4 b = ((const float4*)(wsO + 4194304))[i4];
    const float4 c = ((const float4*)(wsO + 8388608))[i4];
    v.x = (v.x + a.x + b.x + c.x) * inv;
    v.y = (v.y + a.y + b.y + c.y) * inv;
    v.z = (v.z + a.z + b.z + c.z) * inv;
    v.w = (v.w + a.w + b.w + c.w) * inv;
    ((float4*)dOut)[i4] = v;
}

__global__ __launch_bounds__(256) void divide_fin(float* __restrict__ dOut,
                                                  const float* __restrict__ wsl) {
    const int i4 = blockIdx.x * 256 + threadIdx.x;
    const int row = i4 >> 6;
    const float l = wsl[row] + wsl[16384 + row] + wsl[32768 + row] + wsl[49152 + row];
    const float inv = 1.0f / l;
    float4 v = ((const float4*)dOut)[i4];
    v.x *= inv; v.y *= inv; v.z *= inv; v.w *= inv;
    ((float4*)dOut)[i4] = v;
}

extern "C" void kernel_launch(void* const* d_in, const int* in_sizes, int n_in,
                              void* d_out, int out_size, void* d_ws, size_t ws_size,
                              hipStream_t stream) {
    const float* F = (const float*)d_in[0];
    // d_in[1] (masks) has no effect on the output.
    float* out = (float*)d_out;
    char* ws = (char*)d_ws;

    // ws layout: Khi bf16 [4][4096][256] @0 (8MB) | Vt bf16 [4][256][4096] @8MB |
    //            G bf16 [4][4096][256] @16MB | wsl f32 [4][16384] @24MB (256KB) |
    //            wsO f32 3x[4][4096][256] @24.25MB (48MB)
    unsigned short* Khi = (unsigned short*)ws;
    unsigned short* Vt = Khi + 4194304;
    unsigned short* G = Vt + 4194304;
    float* wsl = (float*)(ws + 25165824);
    float* wsO = (float*)(ws + 25165824 + 262144);
    const size_t needA = 25165824u + 262144u + 3u * 16777216u;

    prep_kv<<<dim3(64, 4), 256, 0, stream>>>(F, Khi, Vt);
    prep_g<<<dim3(64, 4), 256, 0, stream>>>(F, G);

    if (ws_size >= needA) {
        attn_main<0><<<dim3(512), 256, 0, stream>>>(Khi, Vt, G, wsl, out, wsO);
        reduce_fin<<<4096, 256, 0, stream>>>(out, wsO, wsl);
    } else {
        hipMemsetAsync(out, 0, 16777216, stream);
        attn_main<1><<<dim3(512), 256, 0, stream>>>(Khi, Vt, G, wsl, out, nullptr);
        divide_fin<<<4096, 256, 0, stream>>>(out, wsl);
    }
}